// Round 8
// baseline (3491.386 us; speedup 1.0000x reference)
//
#include <hip/hip_runtime.h>
#include <hip/hip_bf16.h>

#define B_ 2
#define T_ 512
#define D_ 512
#define H_ 8
#define L_ 6
#define F_ 2048
#define V_ 32000
#define BT_ (B_ * T_)
#define HD_ (H_ * D_)
#define BH_ (B_ * H_)

typedef __attribute__((ext_vector_type(8))) short short8;
typedef __attribute__((ext_vector_type(4))) short short4v;
typedef __attribute__((ext_vector_type(4))) float f32x4;

__device__ __forceinline__ short f2b(float f) {
  __hip_bfloat16 h = __float2bfloat16(f);
  short u; __builtin_memcpy(&u, &h, 2); return u;
}
__device__ __forceinline__ void store_c(float* p, float v) { *p = v; }
__device__ __forceinline__ void store_c(short* p, float v) { *p = f2b(v); }

// ---------------- embedding * sqrt(D) + sinusoidal PE (f32 + bf16 copies) ----------------
__global__ __launch_bounds__(256) void embed_kernel(
    const int* __restrict__ tok, const float* __restrict__ emb,
    float* __restrict__ out, short* __restrict__ out16)
{
  const int row = blockIdx.x;            // b*T + t
  const int t = row & (T_ - 1);
  const int token = tok[row];
  const float* e = emb + (size_t)token * D_;
  float* o = out + (size_t)row * D_;
  short* o16 = out16 + (size_t)row * D_;
  const float scale = sqrtf((float)D_);
  const float nl = -logf(10000.0f);
  for (int d = threadIdx.x; d < D_; d += 256) {
    int i = d >> 1;
    float wl = expf(nl * (2.0f * (float)i) / (float)D_);
    float ang = (float)t * wl;
    float pe = (d & 1) ? cosf(ang) : sinf(ang);
    float v = e[d] * scale + pe;
    o[d] = v; o16[d] = f2b(v);
  }
}

// ---------------- generic MFMA GEMM, 2-deep pipelined ----------------
template<bool BTM, typename OutT, int BM>
__global__ __launch_bounds__(256, BM == 128 ? 2 : 3) void mfma_gemm(
    const short* __restrict__ A, long lda, long a_hi, long a_lo,
    const void* __restrict__ Bv, long ldb, long b_hi, long b_lo,
    OutT* __restrict__ C, long ldc, long c_hi, long c_lo, long pstride,
    short* __restrict__ Ct, int trans_hh, int relu,
    int K, int nh, int ksplit, float scale,
    const float* __restrict__ bias, long bias_stride)
{
  constexpr int SA = BM + 1;
  constexpr int AU = BM / 32;
  constexpr int WRN = (BM == 128) ? 2 : 1;
  constexpr int WN  = (BM == 128) ? 64 : 32;
  constexpr int NR  = WN / 16;
  __shared__ short8 As8[2 * 8 * SA];
  __shared__ short8 Bs8[2 * 8 * 129];
  const int tid = threadIdx.x;
  const int bh = blockIdx.z / ksplit;
  const int kz = blockIdx.z - bh * ksplit;
  const int bb = bh / nh, hh = bh - bb * nh;
  const short* Ab = A + (long)bb * a_hi + (long)hh * a_lo;
  const short* Bbs = (const short*)Bv + (long)bb * b_hi + (long)hh * b_lo;
  const float* Bbf = (const float*)Bv + (long)bb * b_hi + (long)hh * b_lo;
  OutT* Cb = C + (long)bb * c_hi + (long)hh * c_lo + (long)kz * pstride;

  const int gx = gridDim.x, gy = gridDim.y;
  const int nwg = gx * gy;
  int lin = blockIdx.y * gx + blockIdx.x;
  {
    const int xcd = lin & 7, idx = lin >> 3;
    const int q = nwg >> 3, r = nwg & 7;
    lin = (xcd < r ? xcd * (q + 1) : r * (q + 1) + (xcd - r) * q) + idx;
  }
  const int bn = (lin / gy) * 128;
  const int bm = (lin % gy) * BM;

  const int klen = K / ksplit, kbase = kz * klen;
  const int lane = tid & 63, wid = tid >> 6;
  const int wr = (WRN == 2) ? (wid >> 1) : 0;
  const int wc = (WRN == 2) ? (wid & 1) : wid;
  const int lg = lane >> 4, r16 = lane & 15;

  int arow[AU], acol[AU];
#pragma unroll
  for (int u = 0; u < AU; ++u) { int o = u * 256 + tid; arow[u] = o >> 3; acol[u] = o & 7; }
  int brow[4], bcol[4];
#pragma unroll
  for (int u = 0; u < 4; ++u) { int o = u * 256 + tid; brow[u] = o >> 3; bcol[u] = o & 7; }
  const int ncol = tid & 127, nsh = tid >> 7;

  short8 pa0[AU], pa1[AU];
  short8 pbt0[4], pbt1[4];
  float  pbn0[4][8], pbn1[4][8];

#define LOADSET(PA, PBT, PBN, K0)                                               \
  {                                                                             \
    _Pragma("unroll")                                                           \
    for (int u = 0; u < AU; ++u)                                                \
      PA[u] = *(const short8*)(Ab + (long)(bm + arow[u]) * lda + ((K0) + acol[u] * 8)); \
    if constexpr (BTM) {                                                        \
      _Pragma("unroll")                                                         \
      for (int u = 0; u < 4; ++u)                                               \
        PBT[u] = *(const short8*)(Bbs + (long)(bn + brow[u]) * ldb + ((K0) + bcol[u] * 8)); \
    } else {                                                                    \
      const float* s_ = Bbf + (long)((K0) + nsh * 32) * ldb + (bn + ncol);      \
      _Pragma("unroll")                                                         \
      for (int i = 0; i < 4; ++i)                                               \
        _Pragma("unroll")                                                       \
        for (int j = 0; j < 8; ++j)                                             \
          PBN[i][j] = s_[(long)(i * 8 + j) * ldb];                              \
    }                                                                           \
  }

#define STAGESET(PA, PBT, PBN, BUF)                                             \
  {                                                                             \
    const int ao_ = (BUF) * 8 * SA, bo_ = (BUF) * 8 * 129;                      \
    _Pragma("unroll")                                                           \
    for (int u = 0; u < AU; ++u) As8[ao_ + acol[u] * SA + arow[u]] = PA[u];     \
    if constexpr (BTM) {                                                        \
      _Pragma("unroll")                                                         \
      for (int u = 0; u < 4; ++u) Bs8[bo_ + bcol[u] * 129 + brow[u]] = PBT[u];  \
    } else {                                                                    \
      _Pragma("unroll")                                                         \
      for (int i = 0; i < 4; ++i) {                                             \
        short8 v_;                                                              \
        _Pragma("unroll")                                                       \
        for (int j = 0; j < 8; ++j) v_[j] = f2b(PBN[i][j]);                     \
        Bs8[bo_ + (nsh * 4 + i) * 129 + ncol] = v_;                             \
      }                                                                         \
    }                                                                           \
  }

  f32x4 acc[4][NR] = {};
  auto domfma = [&](int buf) {
    const int ao = buf * 8 * SA, bo = buf * 8 * 129;
#pragma unroll
    for (int kb = 0; kb < 2; ++kb) {
      const int cha = ao + (kb * 4 + lg) * SA;
      const int chb = bo + (kb * 4 + lg) * 129;
      short8 a0 = As8[cha + wr * 64 +  0 + r16];
      short8 a1 = As8[cha + wr * 64 + 16 + r16];
      short8 a2 = As8[cha + wr * 64 + 32 + r16];
      short8 a3 = As8[cha + wr * 64 + 48 + r16];
#pragma unroll
      for (int n = 0; n < NR; ++n) {
        short8 bfr = Bs8[chb + wc * WN + n * 16 + r16];
        acc[0][n] = __builtin_amdgcn_mfma_f32_16x16x32_bf16(a0, bfr, acc[0][n], 0, 0, 0);
        acc[1][n] = __builtin_amdgcn_mfma_f32_16x16x32_bf16(a1, bfr, acc[1][n], 0, 0, 0);
        acc[2][n] = __builtin_amdgcn_mfma_f32_16x16x32_bf16(a2, bfr, acc[2][n], 0, 0, 0);
        acc[3][n] = __builtin_amdgcn_mfma_f32_16x16x32_bf16(a3, bfr, acc[3][n], 0, 0, 0);
      }
    }
  };

  const int nsteps = klen >> 6;   // even for all our shapes
  LOADSET(pa0, pbt0, pbn0, kbase)
  STAGESET(pa0, pbt0, pbn0, 0)
  if (nsteps > 1) LOADSET(pa1, pbt1, pbn1, kbase + 64)
  __syncthreads();

  for (int t = 0; t + 1 < nsteps; t += 2) {
    if (t + 2 < nsteps) LOADSET(pa0, pbt0, pbn0, kbase + (t + 2) * 64)
    domfma(0);
    STAGESET(pa1, pbt1, pbn1, 1)
    __syncthreads();
    if (t + 3 < nsteps) LOADSET(pa1, pbt1, pbn1, kbase + (t + 3) * 64)
    domfma(1);
    if (t + 2 < nsteps) {
      STAGESET(pa0, pbt0, pbn0, 0)
      __syncthreads();
    }
  }
#undef LOADSET
#undef STAGESET

  const float* bp = bias ? bias + (long)hh * bias_stride : nullptr;
  if (hh == trans_hh) {
#pragma unroll
    for (int m = 0; m < 4; ++m)
#pragma unroll
      for (int n = 0; n < NR; ++n) {
        const int col = bn + wc * WN + n * 16 + r16;
        const float badd = bp ? bp[col] : 0.0f;
        short4v sv;
#pragma unroll
        for (int rr = 0; rr < 4; ++rr) sv[rr] = f2b(acc[m][n][rr] * scale + badd);
        *(short4v*)(Ct + (long)col * BT_ + (bm + wr * 64 + m * 16 + lg * 4)) = sv;
      }
  } else {
#pragma unroll
    for (int m = 0; m < 4; ++m)
#pragma unroll
      for (int rr = 0; rr < 4; ++rr) {
        const int row = bm + wr * 64 + m * 16 + lg * 4 + rr;
        OutT* crow = Cb + (long)row * ldc + bn + wc * WN + r16;
#pragma unroll
        for (int n = 0; n < NR; ++n) {
          float v = acc[m][n][rr] * scale;
          if (bp) v += bp[bn + wc * WN + n * 16 + r16];
          if (relu) v = fmaxf(v, 0.0f);
          store_c(&crow[n * 16], v);
        }
      }
  }
}

// ---------------- fused flash attention: O = softmax(Q K^T / sqrt(D)) V ----------------
// Block = (bh, 32-q-tile). 4 waves, wave w owns d-chunk w*128.
// K staged to LDS per-wave (coalesced); V (from Vt, k-contig) staged into the SAME
// buffer after QK reads complete. Cross-wave S reduction + online softmax in LDS.
__global__ __launch_bounds__(256, 3) void flash_attn_kernel(
    const short* Q, const short* __restrict__ Kg,
    const short* __restrict__ Vtg, short* O, int causal)
{
  __shared__ short8 KV[4 * 528];          // per-wave: K [16 oct][33] / V [4 oct][129]
  __shared__ float Sred[4][32][33];
  __shared__ short8 Pl[4 * 33];           // P bf16, A-operand layout [k-oct][row]
  __shared__ float rowm[32], rowl[32], rowf[32];

  const int tid = threadIdx.x;
  const int lane = tid & 63, w = tid >> 6;
  const int lg = lane >> 4, r16 = lane & 15;

  // XCD swizzle: 2 bh per XCD so K/V stay L2-resident
  const int lin = blockIdx.y + blockIdx.z * (T_ / 32);
  const int xcd = lin & 7, rr_ = lin >> 3;
  const int qi = rr_ & 15, hi = rr_ >> 4;
  const int bh = xcd * 2 + hi;
  const int b = bh >> 3, hh = bh & 7;
  const int q0 = qi * 32;
  const int dc = w * 128;

  const short* Qbase = Q + ((long)b * T_ + q0) * HD_ + hh * D_ + dc;
  const short* Kbase = Kg + ((long)b * T_) * HD_ + hh * D_ + dc;
  const short* Vbase = Vtg + ((long)(hh * D_ + dc)) * BT_ + (long)b * T_;
  short8* KVw = KV + w * 528;

  short8 qf[2][4];
#pragma unroll
  for (int rg = 0; rg < 2; ++rg)
#pragma unroll
    for (int ks = 0; ks < 4; ++ks)
      qf[rg][ks] = *(const short8*)(Qbase + (long)(rg * 16 + r16) * HD_ + ks * 32 + lg * 8);

  f32x4 o[2][8] = {};
  if (tid < 32) { rowm[tid] = -3.0e38f; rowl[tid] = 0.0f; }

  const int nkv = causal ? (q0 / 32 + 1) : (T_ / 32);
  const float sscale = 0.044194173824159216f;   // 1/sqrt(512)

  for (int kt = 0; kt < nkv; ++kt) {
    __syncthreads();                         // prev PV done (and init visible)
    // ---- stage K (coalesced) ----
#pragma unroll
    for (int i = 0; i < 8; ++i) {
      int idx = i * 64 + lane;
      int tok = idx >> 4, oct = idx & 15;
      KVw[oct * 33 + tok] = *(const short8*)(Kbase + (long)(kt * 32 + tok) * HD_ + oct * 8);
    }
    __syncthreads();
    // ---- QK^T partial over this wave's d-chunk ----
    f32x4 s[2][2] = {};
#pragma unroll
    for (int ks = 0; ks < 4; ++ks) {
#pragma unroll
      for (int ng = 0; ng < 2; ++ng) {
        short8 kb = KVw[(ks * 4 + lg) * 33 + ng * 16 + r16];
        s[0][ng] = __builtin_amdgcn_mfma_f32_16x16x32_bf16(qf[0][ks], kb, s[0][ng], 0, 0, 0);
        s[1][ng] = __builtin_amdgcn_mfma_f32_16x16x32_bf16(qf[1][ks], kb, s[1][ng], 0, 0, 0);
      }
    }
#pragma unroll
    for (int rg = 0; rg < 2; ++rg)
#pragma unroll
      for (int ng = 0; ng < 2; ++ng)
#pragma unroll
        for (int rr = 0; rr < 4; ++rr)
          Sred[w][rg * 16 + lg * 4 + rr][ng * 16 + r16] = s[rg][ng][rr];
    __syncthreads();
    // ---- stage V into same buffer (QK reads done) ----
#pragma unroll
    for (int i = 0; i < 8; ++i) {
      int idx = i * 64 + lane;
      int d = idx & 127, oct = idx >> 7;
      KVw[oct * 129 + d] = *(const short8*)(Vbase + (long)d * BT_ + kt * 32 + oct * 8);
    }
    // ---- online softmax (rows distributed over all threads) ----
    {
      const int row = tid >> 3, sub = tid & 7;
      const int kvb = sub * 4;
      float v0 = Sred[0][row][kvb+0] + Sred[1][row][kvb+0] + Sred[2][row][kvb+0] + Sred[3][row][kvb+0];
      float v1 = Sred[0][row][kvb+1] + Sred[1][row][kvb+1] + Sred[2][row][kvb+1] + Sred[3][row][kvb+1];
      float v2 = Sred[0][row][kvb+2] + Sred[1][row][kvb+2] + Sred[2][row][kvb+2] + Sred[3][row][kvb+2];
      float v3 = Sred[0][row][kvb+3] + Sred[1][row][kvb+3] + Sred[2][row][kvb+3] + Sred[3][row][kvb+3];
      v0 *= sscale; v1 *= sscale; v2 *= sscale; v3 *= sscale;
      if (causal) {
        const int qg = q0 + row, kg = kt * 32 + kvb;
        if (kg + 0 > qg) v0 = -3.0e38f;
        if (kg + 1 > qg) v1 = -3.0e38f;
        if (kg + 2 > qg) v2 = -3.0e38f;
        if (kg + 3 > qg) v3 = -3.0e38f;
      }
      float mx = fmaxf(fmaxf(v0, v1), fmaxf(v2, v3));
      mx = fmaxf(mx, __shfl_xor(mx, 1));
      mx = fmaxf(mx, __shfl_xor(mx, 2));
      mx = fmaxf(mx, __shfl_xor(mx, 4));
      const float mo = rowm[row];
      const float mn = fmaxf(mo, mx);
      const float p0 = expf(v0 - mn), p1 = expf(v1 - mn);
      const float p2 = expf(v2 - mn), p3 = expf(v3 - mn);
      float sm = p0 + p1 + p2 + p3;
      sm += __shfl_xor(sm, 1);
      sm += __shfl_xor(sm, 2);
      sm += __shfl_xor(sm, 4);
      const float f = expf(mo - mn);
      if (sub == 0) { rowl[row] = rowl[row] * f + sm; rowm[row] = mn; rowf[row] = f; }
      short* Pls = (short*)Pl;
      const int oct = sub >> 1;
      short4v pv;
      pv[0] = f2b(p0); pv[1] = f2b(p1); pv[2] = f2b(p2); pv[3] = f2b(p3);
      *(short4v*)(Pls + ((long)(oct * 33) + row) * 8 + (sub & 1) * 4) = pv;
    }
    __syncthreads();
    // ---- PV: rescale O then accumulate ----
#pragma unroll
    for (int rg = 0; rg < 2; ++rg) {
      const float f0 = rowf[rg * 16 + lg * 4 + 0];
      const float f1 = rowf[rg * 16 + lg * 4 + 1];
      const float f2 = rowf[rg * 16 + lg * 4 + 2];
      const float f3 = rowf[rg * 16 + lg * 4 + 3];
      short8 a = Pl[lg * 33 + rg * 16 + r16];
#pragma unroll
      for (int ng = 0; ng < 8; ++ng) {
        o[rg][ng][0] *= f0; o[rg][ng][1] *= f1; o[rg][ng][2] *= f2; o[rg][ng][3] *= f3;
        short8 vb = KVw[lg * 129 + ng * 16 + r16];
        o[rg][ng] = __builtin_amdgcn_mfma_f32_16x16x32_bf16(a, vb, o[rg][ng], 0, 0, 0);
      }
    }
  }
  // ---- epilogue: normalize + store ----
  short* Obase = O + ((long)b * T_ + q0) * HD_ + hh * D_ + dc;
#pragma unroll
  for (int rg = 0; rg < 2; ++rg)
#pragma unroll
    for (int rr = 0; rr < 4; ++rr) {
      const int row = rg * 16 + lg * 4 + rr;
      const float inv = 1.0f / rowl[row];
#pragma unroll
      for (int ng = 0; ng < 8; ++ng)
        Obase[(long)row * HD_ + ng * 16 + r16] = f2b(o[rg][ng][rr] * inv);
    }
}

// ---- fused: x = resid + bias + sum_z partial; resid(f32) = LN(x)*g+b; + bf16 copy ----
__global__ __launch_bounds__(256) void reduce_ln_kernel(
    const float* __restrict__ P, long pstride, int ks,
    const float* __restrict__ bias, float* __restrict__ hbuf, short* __restrict__ h16,
    const float* __restrict__ gam, const float* __restrict__ bet)
{
  __shared__ float red[256];
  const int row = blockIdx.x, tid = threadIdx.x;
  const long base = (long)row * D_;
  float s0 = hbuf[base + tid] + bias[tid];
  float s1 = hbuf[base + tid + 256] + bias[tid + 256];
  for (int z = 0; z < ks; ++z) {
    s0 += P[(long)z * pstride + base + tid];
    s1 += P[(long)z * pstride + base + tid + 256];
  }
  red[tid] = s0 + s1; __syncthreads();
  for (int o = 128; o > 0; o >>= 1) { if (tid < o) red[tid] += red[tid + o]; __syncthreads(); }
  const float mean = red[0] * (1.0f / D_); __syncthreads();
  const float d0 = s0 - mean, d1 = s1 - mean;
  red[tid] = d0 * d0 + d1 * d1; __syncthreads();
  for (int o = 128; o > 0; o >>= 1) { if (tid < o) red[tid] += red[tid + o]; __syncthreads(); }
  const float inv = rsqrtf(red[0] * (1.0f / D_) + 1e-6f);
  const float v0 = d0 * inv * gam[tid] + bet[tid];
  const float v1 = d1 * inv * gam[tid + 256] + bet[tid + 256];
  hbuf[base + tid] = v0;       h16[base + tid] = f2b(v0);
  hbuf[base + tid + 256] = v1; h16[base + tid + 256] = f2b(v1);
}

extern "C" void kernel_launch(void* const* d_in, const int* in_sizes, int n_in,
                              void* d_out, int out_size, void* d_ws, size_t ws_size,
                              hipStream_t stream)
{
  const int*   x         = (const int*)d_in[0];
  const int*   y         = (const int*)d_in[1];
  const float* enc_emb   = (const float*)d_in[2];
  const float* dec_emb   = (const float*)d_in[3];
  const float* enc_qkv_w = (const float*)d_in[4];
  const float* enc_qkv_b = (const float*)d_in[5];
  const float* enc_out_w = (const float*)d_in[6];
  const float* enc_out_b = (const float*)d_in[7];
  const float* enc_ln1_g = (const float*)d_in[8];
  const float* enc_ln1_b = (const float*)d_in[9];
  const float* enc_ff_w1 = (const float*)d_in[10];
  const float* enc_ff_b1 = (const float*)d_in[11];
  const float* enc_ff_w2 = (const float*)d_in[12];
  const float* enc_ff_b2 = (const float*)d_in[13];
  const float* enc_ln2_g = (const float*)d_in[14];
  const float* enc_ln2_b = (const float*)d_in[15];
  const float* dec_sa_qkv_w = (const float*)d_in[16];
  const float* dec_sa_qkv_b = (const float*)d_in[17];
  const float* dec_sa_out_w = (const float*)d_in[18];
  const float* dec_sa_out_b = (const float*)d_in[19];
  const float* dec_ln1_g = (const float*)d_in[20];
  const float* dec_ln1_b = (const float*)d_in[21];
  const float* dec_ca_qkv_w = (const float*)d_in[22];
  const float* dec_ca_qkv_b = (const float*)d_in[23];
  const float* dec_ca_out_w = (const float*)d_in[24];
  const float* dec_ca_out_b = (const float*)d_in[25];
  const float* dec_ln2_g = (const float*)d_in[26];
  const float* dec_ln2_b = (const float*)d_in[27];
  const float* dec_ff_w1 = (const float*)d_in[28];
  const float* dec_ff_b1 = (const float*)d_in[29];
  const float* dec_ff_w2 = (const float*)d_in[30];
  const float* dec_ff_b2 = (const float*)d_in[31];
  const float* dec_ln3_g = (const float*)d_in[32];
  const float* dec_ln3_b = (const float*)d_in[33];
  const float* head_w    = (const float*)d_in[34];
  const float* head_b    = (const float*)d_in[35];
  float* out = (float*)d_out;

  // ---- workspace carve-up ----
  char* wsb = (char*)d_ws;
  size_t off = 0;
  auto carve = [&](size_t bytes) { char* p = wsb + off; off += (bytes + 255) & ~255ull; return p; };
  float* h    = (float*)carve((size_t)BT_ * D_ * 4);
  float* dd   = (float*)carve((size_t)BT_ * D_ * 4);
  short* hb16 = (short*)carve((size_t)BT_ * D_ * 2);
  short* db16 = (short*)carve((size_t)BT_ * D_ * 2);
  short* Qb   = (short*)carve((size_t)BT_ * HD_ * 2);
  short* Kb   = (short*)carve((size_t)BT_ * HD_ * 2);
  short* Vt   = (short*)carve((size_t)HD_ * BT_ * 2);
  float* Sb   = (float*)carve((size_t)BH_ * T_ * T_ * 4);  // split-K partials
  short* Ob   = Qb;   // flash reads its Q slice before writing the same slice
  short* mid  = Qb;   // attn buffers dead during FFN
  (void)ws_size;

  dim3 blk(256);
  const long THD = (long)T_ * HD_;
  const long WQKV = (long)D_ * HD_;

  auto gemm = [&](bool bt, bool of32, bool bm64, int relu,
                  const short* A, long lda, long a_hi, long a_lo,
                  const void* Bp, long ldb, long b_hi, long b_lo,
                  void* Cp, long ldc, long c_hi, long c_lo, long pstride,
                  short* Ct, int trans_hh,
                  int M, int N, int K, int batch, int nh, int ksplit,
                  float scale, const float* bias, long bstride) {
    dim3 grd(N / 128, M / (bm64 ? 64 : 128), batch * ksplit);
    if (bm64) {
      if (bt) {
        if (of32) mfma_gemm<true , float, 64><<<grd, blk, 0, stream>>>(A, lda, a_hi, a_lo, Bp, ldb, b_hi, b_lo,
            (float*)Cp, ldc, c_hi, c_lo, pstride, Ct, trans_hh, relu, K, nh, ksplit, scale, bias, bstride);
        else      mfma_gemm<true , short, 64><<<grd, blk, 0, stream>>>(A, lda, a_hi, a_lo, Bp, ldb, b_hi, b_lo,
            (short*)Cp, ldc, c_hi, c_lo, pstride, Ct, trans_hh, relu, K, nh, ksplit, scale, bias, bstride);
      } else {
        if (of32) mfma_gemm<false, float, 64><<<grd, blk, 0, stream>>>(A, lda, a_hi, a_lo, Bp, ldb, b_hi, b_lo,
            (float*)Cp, ldc, c_hi, c_lo, pstride, Ct, trans_hh, relu, K, nh, ksplit, scale, bias, bstride);
        else      mfma_gemm<false, short, 64><<<grd, blk, 0, stream>>>(A, lda, a_hi, a_lo, Bp, ldb, b_hi, b_lo,
            (short*)Cp, ldc, c_hi, c_lo, pstride, Ct, trans_hh, relu, K, nh, ksplit, scale, bias, bstride);
      }
    } else {
      if (of32) mfma_gemm<false, float, 128><<<grd, blk, 0, stream>>>(A, lda, a_hi, a_lo, Bp, ldb, b_hi, b_lo,
          (float*)Cp, ldc, c_hi, c_lo, pstride, Ct, trans_hh, relu, K, nh, ksplit, scale, bias, bstride);
      else      mfma_gemm<false, short, 128><<<grd, blk, 0, stream>>>(A, lda, a_hi, a_lo, Bp, ldb, b_hi, b_lo,
          (short*)Cp, ldc, c_hi, c_lo, pstride, Ct, trans_hh, relu, K, nh, ksplit, scale, bias, bstride);
    }
  };

  auto attention = [&](const short* qsrc, const short* kvsrc, bool self,
                       const float* qkvw, const float* qkvb,
                       const float* ow, const float* ob,
                       float* resid, short* resid16, int causal,
                       const float* lng, const float* lnb) {
    if (self) {
      gemm(false, false, false, 0, qsrc, D_, 0, 0, qkvw, HD_, 0, WQKV,
           Qb, HD_, 0, (long)(Kb - Qb), 0, Vt, 2,
           BT_, HD_, D_, 3, 3, 1, 1.0f, qkvb, HD_);
    } else {
      gemm(false, false, false, 0, qsrc, D_, 0, 0, qkvw, HD_, 0, 0,
           Qb, HD_, 0, 0, 0, nullptr, -1,
           BT_, HD_, D_, 1, 1, 1, 1.0f, qkvb, 0);
      gemm(false, false, false, 0, kvsrc, D_, 0, 0, qkvw + WQKV, HD_, 0, WQKV,
           Kb, HD_, 0, 0, 0, Vt, 1,
           BT_, HD_, D_, 2, 2, 1, 1.0f, qkvb + HD_, HD_);
    }
    // fused QK^T + softmax + PV
    flash_attn_kernel<<<dim3(1, T_ / 32, BH_), blk, 0, stream>>>(Qb, Kb, Vt, Ob, causal);
    // out-projection split-K=8 -> f32 partials in Sb; fused reduce+resid+LN
    gemm(false, true, false, 0, Ob, HD_, 0, 0, ow, D_, 0, 0,
         Sb, D_, 0, 0, (long)BT_ * D_, nullptr, -1,
         BT_, D_, HD_, 1, 1, 8, 1.0f, nullptr, 0);
    reduce_ln_kernel<<<dim3(BT_), blk, 0, stream>>>(
        Sb, (long)BT_ * D_, 8, ob, resid, resid16, lng, lnb);
  };

  auto ffn = [&](float* resid, short* resid16,
                 const float* w1, const float* b1,
                 const float* w2, const float* b2,
                 const float* lng, const float* lnb) {
    gemm(false, false, true, 1, resid16, D_, 0, 0, w1, F_, 0, 0,
         mid, F_, 0, 0, 0, nullptr, -1,
         BT_, F_, D_, 1, 1, 1, 1.0f, b1, 0);
    gemm(false, true, false, 0, mid, F_, 0, 0, w2, D_, 0, 0,
         Sb, D_, 0, 0, (long)BT_ * D_, nullptr, -1,
         BT_, D_, F_, 1, 1, 8, 1.0f, nullptr, 0);
    reduce_ln_kernel<<<dim3(BT_), blk, 0, stream>>>(
        Sb, (long)BT_ * D_, 8, b2, resid, resid16, lng, lnb);
  };

  // ---------------- encoder ----------------
  embed_kernel<<<dim3(BT_), blk, 0, stream>>>(x, enc_emb, h, hb16);
  for (int i = 0; i < L_; ++i) {
    attention(hb16, hb16, true,
              enc_qkv_w + (size_t)i * 3 * WQKV, enc_qkv_b + (size_t)i * 3 * HD_,
              enc_out_w + (size_t)i * HD_ * D_, enc_out_b + (size_t)i * D_,
              h, hb16, 0, enc_ln1_g + (size_t)i * D_, enc_ln1_b + (size_t)i * D_);
    ffn(h, hb16, enc_ff_w1 + (size_t)i * D_ * F_, enc_ff_b1 + (size_t)i * F_,
        enc_ff_w2 + (size_t)i * F_ * D_, enc_ff_b2 + (size_t)i * D_,
        enc_ln2_g + (size_t)i * D_, enc_ln2_b + (size_t)i * D_);
  }

  // ---------------- decoder ----------------
  embed_kernel<<<dim3(BT_), blk, 0, stream>>>(y, dec_emb, dd, db16);
  for (int i = 0; i < L_; ++i) {
    attention(db16, db16, true,
              dec_sa_qkv_w + (size_t)i * 3 * WQKV, dec_sa_qkv_b + (size_t)i * 3 * HD_,
              dec_sa_out_w + (size_t)i * HD_ * D_, dec_sa_out_b + (size_t)i * D_,
              dd, db16, 1, dec_ln1_g + (size_t)i * D_, dec_ln1_b + (size_t)i * D_);
    attention(db16, hb16, false,
              dec_ca_qkv_w + (size_t)i * 3 * WQKV, dec_ca_qkv_b + (size_t)i * 3 * HD_,
              dec_ca_out_w + (size_t)i * HD_ * D_, dec_ca_out_b + (size_t)i * D_,
              dd, db16, 0, dec_ln2_g + (size_t)i * D_, dec_ln2_b + (size_t)i * D_);
    ffn(dd, db16, dec_ff_w1 + (size_t)i * D_ * F_, dec_ff_b1 + (size_t)i * F_,
        dec_ff_w2 + (size_t)i * F_ * D_, dec_ff_b2 + (size_t)i * D_,
        dec_ln3_g + (size_t)i * D_, dec_ln3_b + (size_t)i * D_);
  }

  // ---------------- LM head -> f32 logits ----------------
  gemm(false, true, false, 0, db16, D_, 0, 0, head_w, V_, 0, 0,
       out, V_, 0, 0, 0, nullptr, -1,
       BT_, V_, D_, 1, 1, 1, 1.0f, head_b, 0);
}

// Round 9
// 3162.187 us; speedup vs baseline: 1.1041x; 1.1041x over previous
//
#include <hip/hip_runtime.h>
#include <hip/hip_bf16.h>

#define B_ 2
#define T_ 512
#define D_ 512
#define H_ 8
#define L_ 6
#define F_ 2048
#define V_ 32000
#define BT_ (B_ * T_)
#define HD_ (H_ * D_)
#define BH_ (B_ * H_)

typedef __attribute__((ext_vector_type(8))) short short8;
typedef __attribute__((ext_vector_type(4))) short short4v;
typedef __attribute__((ext_vector_type(4))) float f32x4;

__device__ __forceinline__ short f2b(float f) {
  __hip_bfloat16 h = __float2bfloat16(f);
  short u; __builtin_memcpy(&u, &h, 2); return u;
}
__device__ __forceinline__ void store_c(float* p, float v) { *p = v; }
__device__ __forceinline__ void store_c(short* p, float v) { *p = f2b(v); }

// ---------------- embedding * sqrt(D) + sinusoidal PE (f32 + bf16 copies) ----------------
__global__ __launch_bounds__(256) void embed_kernel(
    const int* __restrict__ tok, const float* __restrict__ emb,
    float* __restrict__ out, short* __restrict__ out16)
{
  const int row = blockIdx.x;            // b*T + t
  const int t = row & (T_ - 1);
  const int token = tok[row];
  const float* e = emb + (size_t)token * D_;
  float* o = out + (size_t)row * D_;
  short* o16 = out16 + (size_t)row * D_;
  const float scale = sqrtf((float)D_);
  const float nl = -logf(10000.0f);
  for (int d = threadIdx.x; d < D_; d += 256) {
    int i = d >> 1;
    float wl = expf(nl * (2.0f * (float)i) / (float)D_);
    float ang = (float)t * wl;
    float pe = (d & 1) ? cosf(ang) : sinf(ang);
    float v = e[d] * scale + pe;
    o[d] = v; o16[d] = f2b(v);
  }
}

// ---------------- generic MFMA GEMM (r6 structure: single-buffer + reg prefetch) --------
// A: bf16 [.,K] k-contig. B: BTM ? bf16 [N][K] k-contig : f32 [K][N].
// BM in {64,128}, BN=128. z = batch(nh) x ksplit. Optional transposed bf16
// store for hh==trans_hh; optional fused relu epilogue.
template<bool BTM, typename OutT, int BM>
__global__ __launch_bounds__(256, 3) void mfma_gemm(
    const short* __restrict__ A, long lda, long a_hi, long a_lo,
    const void* __restrict__ Bv, long ldb, long b_hi, long b_lo,
    OutT* __restrict__ C, long ldc, long c_hi, long c_lo, long pstride,
    short* __restrict__ Ct, int trans_hh, int relu,
    int K, int nh, int ksplit, float scale,
    const float* __restrict__ bias, long bias_stride)
{
  constexpr int SA = BM + 1;
  constexpr int AU = BM / 32;
  constexpr int WRN = (BM == 128) ? 2 : 1;
  constexpr int WN  = (BM == 128) ? 64 : 32;
  constexpr int NR  = WN / 16;
  __shared__ short8 As8[8 * SA];
  __shared__ short8 Bs8[8 * 129];
  const int tid = threadIdx.x;
  const int bh = blockIdx.z / ksplit;
  const int kz = blockIdx.z - bh * ksplit;
  const int bb = bh / nh, hh = bh - bb * nh;
  const short* Ab = A + (long)bb * a_hi + (long)hh * a_lo;
  const short* Bbs = (const short*)Bv + (long)bb * b_hi + (long)hh * b_lo;
  const float* Bbf = (const float*)Bv + (long)bb * b_hi + (long)hh * b_lo;
  OutT* Cb = C + (long)bb * c_hi + (long)hh * c_lo + (long)kz * pstride;

  const int gx = gridDim.x, gy = gridDim.y;
  const int nwg = gx * gy;
  int lin = blockIdx.y * gx + blockIdx.x;
  {
    const int xcd = lin & 7, idx = lin >> 3;
    const int q = nwg >> 3, r = nwg & 7;
    lin = (xcd < r ? xcd * (q + 1) : r * (q + 1) + (xcd - r) * q) + idx;
  }
  const int bn = (lin / gy) * 128;
  const int bm = (lin % gy) * BM;

  const int klen = K / ksplit, kbase = kz * klen;
  const int lane = tid & 63, wid = tid >> 6;
  const int wr = (WRN == 2) ? (wid >> 1) : 0;
  const int wc = (WRN == 2) ? (wid & 1) : wid;
  const int lg = lane >> 4, r16 = lane & 15;

  int arow[AU], acol[AU];
#pragma unroll
  for (int u = 0; u < AU; ++u) { int o = u * 256 + tid; arow[u] = o >> 3; acol[u] = o & 7; }
  int brow[4], bcol[4];
#pragma unroll
  for (int u = 0; u < 4; ++u) { int o = u * 256 + tid; brow[u] = o >> 3; bcol[u] = o & 7; }
  const int ncol = tid & 127, nsh = tid >> 7;

  short8 pa[AU];
  short8 pbt[4];
  float  pbn[4][8];

  auto load = [&](int k0) {
#pragma unroll
    for (int u = 0; u < AU; ++u)
      pa[u] = *(const short8*)(Ab + (long)(bm + arow[u]) * lda + (k0 + acol[u] * 8));
    if constexpr (BTM) {
#pragma unroll
      for (int u = 0; u < 4; ++u)
        pbt[u] = *(const short8*)(Bbs + (long)(bn + brow[u]) * ldb + (k0 + bcol[u] * 8));
    } else {
      const float* s = Bbf + (long)(k0 + nsh * 32) * ldb + (bn + ncol);
#pragma unroll
      for (int i = 0; i < 4; ++i)
#pragma unroll
        for (int j = 0; j < 8; ++j)
          pbn[i][j] = s[(long)(i * 8 + j) * ldb];
    }
  };
  auto stage = [&]() {
#pragma unroll
    for (int u = 0; u < AU; ++u) As8[acol[u] * SA + arow[u]] = pa[u];
    if constexpr (BTM) {
#pragma unroll
      for (int u = 0; u < 4; ++u) Bs8[bcol[u] * 129 + brow[u]] = pbt[u];
    } else {
#pragma unroll
      for (int i = 0; i < 4; ++i) {
        short8 v;
#pragma unroll
        for (int j = 0; j < 8; ++j) v[j] = f2b(pbn[i][j]);
        Bs8[(nsh * 4 + i) * 129 + ncol] = v;
      }
    }
  };

  f32x4 acc[4][NR] = {};
  auto domfma = [&]() {
#pragma unroll
    for (int kb = 0; kb < 2; ++kb) {
      const int cha = (kb * 4 + lg) * SA;
      const int chb = (kb * 4 + lg) * 129;
      short8 a0 = As8[cha + wr * 64 +  0 + r16];
      short8 a1 = As8[cha + wr * 64 + 16 + r16];
      short8 a2 = As8[cha + wr * 64 + 32 + r16];
      short8 a3 = As8[cha + wr * 64 + 48 + r16];
#pragma unroll
      for (int n = 0; n < NR; ++n) {
        short8 bfr = Bs8[chb + wc * WN + n * 16 + r16];
        acc[0][n] = __builtin_amdgcn_mfma_f32_16x16x32_bf16(a0, bfr, acc[0][n], 0, 0, 0);
        acc[1][n] = __builtin_amdgcn_mfma_f32_16x16x32_bf16(a1, bfr, acc[1][n], 0, 0, 0);
        acc[2][n] = __builtin_amdgcn_mfma_f32_16x16x32_bf16(a2, bfr, acc[2][n], 0, 0, 0);
        acc[3][n] = __builtin_amdgcn_mfma_f32_16x16x32_bf16(a3, bfr, acc[3][n], 0, 0, 0);
      }
    }
  };

  load(kbase);
  stage();
  __syncthreads();
  const int nsteps = klen >> 6;
  for (int t = 0; t < nsteps; ++t) {
    const bool more = (t + 1 < nsteps);
    if (more) load(kbase + (t + 1) * 64);
    domfma();
    if (more) { __syncthreads(); stage(); __syncthreads(); }
  }

  const float* bp = bias ? bias + (long)hh * bias_stride : nullptr;
  if (hh == trans_hh) {
#pragma unroll
    for (int m = 0; m < 4; ++m)
#pragma unroll
      for (int n = 0; n < NR; ++n) {
        const int col = bn + wc * WN + n * 16 + r16;
        const float badd = bp ? bp[col] : 0.0f;
        short4v sv;
#pragma unroll
        for (int rr = 0; rr < 4; ++rr) sv[rr] = f2b(acc[m][n][rr] * scale + badd);
        *(short4v*)(Ct + (long)col * BT_ + (bm + wr * 64 + m * 16 + lg * 4)) = sv;
      }
  } else {
#pragma unroll
    for (int m = 0; m < 4; ++m)
#pragma unroll
      for (int rr = 0; rr < 4; ++rr) {
        const int row = bm + wr * 64 + m * 16 + lg * 4 + rr;
        OutT* crow = Cb + (long)row * ldc + bn + wc * WN + r16;
#pragma unroll
        for (int n = 0; n < NR; ++n) {
          float v = acc[m][n][rr] * scale;
          if (bp) v += bp[bn + wc * WN + n * 16 + r16];
          if (relu) v = fmaxf(v, 0.0f);
          store_c(&crow[n * 16], v);
        }
      }
  }
}

// ---------------- fused QK^T + softmax -> P(bf16) ----------------
// Block = (q-tile of 64 rows, bh); 4 waves, each owning 16 COMPLETE rows
// (full 512-col dot products) -> softmax is wave-local (no LDS reduce).
// K-matrix tile (up to 512 tok x 64 d bf16) staged in LDS per d-step.
// Causal: wave-uniform frag limit (static unroll + uniform guard).
__global__ __launch_bounds__(256, 2) void qksm_kernel(
    const short* __restrict__ Q, const short* __restrict__ Kg,
    short* __restrict__ P, int causal)
{
  __shared__ short8 Buf[4224];        // K-stage 8*513=4104; P-transpose 64*528/8=4224
  short* LDSP = (short*)Buf;

  const int tid = threadIdx.x;
  const int lane = tid & 63, w = tid >> 6;
  const int lg = lane >> 4, r16 = lane & 15;

  // chunked XCD swizzle: XCD x serves bh {2x, 2x+1}
  int lin = blockIdx.y * 8 + blockIdx.x;
  { const int xcd = lin & 7, idx = lin >> 3; lin = xcd * 16 + idx; }
  const int bh = lin >> 3, qt = lin & 7;
  const int b = bh >> 3, hh = bh & 7;
  const int q0 = qt * 64;

  const int nlim = causal ? (qt * 4 + w + 1) : 32;   // valid 16-col frags for this wave
  const int ntok = causal ? (q0 + 64) : T_;

  // Q fragments (A-operand: row = lane&15): wave w covers rows q0+w*16..+15
  const short* Qrow = Q + ((long)b * T_ + q0 + w * 16 + r16) * HD_ + hh * D_;
  short8 qf[8][2];
#pragma unroll
  for (int s = 0; s < 8; ++s)
#pragma unroll
    for (int kb = 0; kb < 2; ++kb)
      qf[s][kb] = *(const short8*)(Qrow + s * 64 + kb * 32 + lg * 8);

  const short* Kbase = Kg + ((long)b * T_) * HD_ + hh * D_;

  f32x4 sacc[32];
#pragma unroll
  for (int n = 0; n < 32; ++n) sacc[n] = (f32x4){0.f, 0.f, 0.f, 0.f};

#pragma unroll
  for (int s = 0; s < 8; ++s) {
    // stage K tile [ntok][64 d] as [d-chunk 0..7][token]
#pragma unroll
    for (int i = 0; i < 16; ++i) {
      int idx = i * 256 + tid;
      int tok = idx >> 3, c = idx & 7;
      if (tok < ntok)
        Buf[c * 513 + tok] = *(const short8*)(Kbase + (long)tok * HD_ + s * 64 + c * 8);
    }
    __syncthreads();
#pragma unroll
    for (int kb = 0; kb < 2; ++kb) {
#pragma unroll
      for (int n = 0; n < 32; ++n) {
        if (n < nlim) {
          short8 bfr = Buf[(kb * 4 + lg) * 513 + n * 16 + r16];
          sacc[n] = __builtin_amdgcn_mfma_f32_16x16x32_bf16(qf[s][kb], bfr, sacc[n], 0, 0, 0);
        }
      }
    }
    __syncthreads();
  }

  // ---- wave-local softmax: lane holds rows lg*4+rr, cols n*16+r16 ----
  const float sscale = 0.044194173824159216f;     // 1/sqrt(512)
  const int qrow = q0 + w * 16 + lg * 4;
  float mx[4] = {-3.0e38f, -3.0e38f, -3.0e38f, -3.0e38f};
#pragma unroll
  for (int n = 0; n < 32; ++n) {
    if (n < nlim) {
      const int col = n * 16 + r16;
#pragma unroll
      for (int rr = 0; rr < 4; ++rr) {
        float v = sacc[n][rr] * sscale;
        if (causal && col > qrow + rr) v = -3.0e38f;
        sacc[n][rr] = v;
        mx[rr] = fmaxf(mx[rr], v);
      }
    }
  }
#pragma unroll
  for (int rr = 0; rr < 4; ++rr) {
    mx[rr] = fmaxf(mx[rr], __shfl_xor(mx[rr], 1));
    mx[rr] = fmaxf(mx[rr], __shfl_xor(mx[rr], 2));
    mx[rr] = fmaxf(mx[rr], __shfl_xor(mx[rr], 4));
    mx[rr] = fmaxf(mx[rr], __shfl_xor(mx[rr], 8));
  }
  float sum[4] = {0.f, 0.f, 0.f, 0.f};
#pragma unroll
  for (int n = 0; n < 32; ++n) {
    if (n < nlim) {
#pragma unroll
      for (int rr = 0; rr < 4; ++rr) {
        float p = expf(sacc[n][rr] - mx[rr]);
        sacc[n][rr] = p;
        sum[rr] += p;
      }
    }
  }
#pragma unroll
  for (int rr = 0; rr < 4; ++rr) {
    sum[rr] += __shfl_xor(sum[rr], 1);
    sum[rr] += __shfl_xor(sum[rr], 2);
    sum[rr] += __shfl_xor(sum[rr], 4);
    sum[rr] += __shfl_xor(sum[rr], 8);
  }
  float inv[4];
#pragma unroll
  for (int rr = 0; rr < 4; ++rr) inv[rr] = 1.0f / sum[rr];

  // ---- P -> LDS (transpose to row-major k-contig), zero invalid, then coalesced store
#pragma unroll
  for (int n = 0; n < 32; ++n) {
    const int col = n * 16 + r16;
#pragma unroll
    for (int rr = 0; rr < 4; ++rr) {
      float val = (n < nlim) ? sacc[n][rr] * inv[rr] : 0.0f;
      LDSP[(w * 16 + lg * 4 + rr) * 528 + col] = f2b(val);
    }
  }
  __syncthreads();
  short* Pout = P + (long)bh * T_ * T_ + (long)q0 * T_;
#pragma unroll
  for (int i = 0; i < 16; ++i) {
    int idx = i * 256 + tid;
    int row = idx >> 6, c8 = idx & 63;
    *(short8*)(Pout + (long)row * T_ + c8 * 8) = *(short8*)(LDSP + row * 528 + c8 * 8);
  }
}

// ---- fused: x = resid + bias + sum_z partial; resid(f32) = LN(x)*g+b; + bf16 copy ----
__global__ __launch_bounds__(256) void reduce_ln_kernel(
    const float* __restrict__ P, long pstride, int ks,
    const float* __restrict__ bias, float* __restrict__ hbuf, short* __restrict__ h16,
    const float* __restrict__ gam, const float* __restrict__ bet)
{
  __shared__ float red[256];
  const int row = blockIdx.x, tid = threadIdx.x;
  const long base = (long)row * D_;
  float s0 = hbuf[base + tid] + bias[tid];
  float s1 = hbuf[base + tid + 256] + bias[tid + 256];
  for (int z = 0; z < ks; ++z) {
    s0 += P[(long)z * pstride + base + tid];
    s1 += P[(long)z * pstride + base + tid + 256];
  }
  red[tid] = s0 + s1; __syncthreads();
  for (int o = 128; o > 0; o >>= 1) { if (tid < o) red[tid] += red[tid + o]; __syncthreads(); }
  const float mean = red[0] * (1.0f / D_); __syncthreads();
  const float d0 = s0 - mean, d1 = s1 - mean;
  red[tid] = d0 * d0 + d1 * d1; __syncthreads();
  for (int o = 128; o > 0; o >>= 1) { if (tid < o) red[tid] += red[tid + o]; __syncthreads(); }
  const float inv = rsqrtf(red[0] * (1.0f / D_) + 1e-6f);
  const float v0 = d0 * inv * gam[tid] + bet[tid];
  const float v1 = d1 * inv * gam[tid + 256] + bet[tid + 256];
  hbuf[base + tid] = v0;       h16[base + tid] = f2b(v0);
  hbuf[base + tid + 256] = v1; h16[base + tid + 256] = f2b(v1);
}

extern "C" void kernel_launch(void* const* d_in, const int* in_sizes, int n_in,
                              void* d_out, int out_size, void* d_ws, size_t ws_size,
                              hipStream_t stream)
{
  const int*   x         = (const int*)d_in[0];
  const int*   y         = (const int*)d_in[1];
  const float* enc_emb   = (const float*)d_in[2];
  const float* dec_emb   = (const float*)d_in[3];
  const float* enc_qkv_w = (const float*)d_in[4];
  const float* enc_qkv_b = (const float*)d_in[5];
  const float* enc_out_w = (const float*)d_in[6];
  const float* enc_out_b = (const float*)d_in[7];
  const float* enc_ln1_g = (const float*)d_in[8];
  const float* enc_ln1_b = (const float*)d_in[9];
  const float* enc_ff_w1 = (const float*)d_in[10];
  const float* enc_ff_b1 = (const float*)d_in[11];
  const float* enc_ff_w2 = (const float*)d_in[12];
  const float* enc_ff_b2 = (const float*)d_in[13];
  const float* enc_ln2_g = (const float*)d_in[14];
  const float* enc_ln2_b = (const float*)d_in[15];
  const float* dec_sa_qkv_w = (const float*)d_in[16];
  const float* dec_sa_qkv_b = (const float*)d_in[17];
  const float* dec_sa_out_w = (const float*)d_in[18];
  const float* dec_sa_out_b = (const float*)d_in[19];
  const float* dec_ln1_g = (const float*)d_in[20];
  const float* dec_ln1_b = (const float*)d_in[21];
  const float* dec_ca_qkv_w = (const float*)d_in[22];
  const float* dec_ca_qkv_b = (const float*)d_in[23];
  const float* dec_ca_out_w = (const float*)d_in[24];
  const float* dec_ca_out_b = (const float*)d_in[25];
  const float* dec_ln2_g = (const float*)d_in[26];
  const float* dec_ln2_b = (const float*)d_in[27];
  const float* dec_ff_w1 = (const float*)d_in[28];
  const float* dec_ff_b1 = (const float*)d_in[29];
  const float* dec_ff_w2 = (const float*)d_in[30];
  const float* dec_ff_b2 = (const float*)d_in[31];
  const float* dec_ln3_g = (const float*)d_in[32];
  const float* dec_ln3_b = (const float*)d_in[33];
  const float* head_w    = (const float*)d_in[34];
  const float* head_b    = (const float*)d_in[35];
  float* out = (float*)d_out;

  // ---- workspace carve-up ----
  char* wsb = (char*)d_ws;
  size_t off = 0;
  auto carve = [&](size_t bytes) { char* p = wsb + off; off += (bytes + 255) & ~255ull; return p; };
  float* h    = (float*)carve((size_t)BT_ * D_ * 4);
  float* dd   = (float*)carve((size_t)BT_ * D_ * 4);
  short* hb16 = (short*)carve((size_t)BT_ * D_ * 2);
  short* db16 = (short*)carve((size_t)BT_ * D_ * 2);
  short* Qb   = (short*)carve((size_t)BT_ * HD_ * 2);
  short* Kb   = (short*)carve((size_t)BT_ * HD_ * 2);
  short* Vt   = (short*)carve((size_t)HD_ * BT_ * 2);
  float* Sb   = (float*)carve((size_t)BH_ * T_ * T_ * 4);  // split-K partials
  short* Pb   = (short*)carve((size_t)BH_ * T_ * T_ * 2);
  short* Ob   = Qb;   // Q dead after qksm
  short* mid  = Qb;   // attn buffers dead during FFN
  (void)ws_size;

  dim3 blk(256);
  const long THD = (long)T_ * HD_;
  const long WQKV = (long)D_ * HD_;

  auto gemm = [&](bool bt, bool of32, bool bm64, int relu,
                  const short* A, long lda, long a_hi, long a_lo,
                  const void* Bp, long ldb, long b_hi, long b_lo,
                  void* Cp, long ldc, long c_hi, long c_lo, long pstride,
                  short* Ct, int trans_hh,
                  int M, int N, int K, int batch, int nh, int ksplit,
                  float scale, const float* bias, long bstride) {
    dim3 grd(N / 128, M / (bm64 ? 64 : 128), batch * ksplit);
    if (bm64) {
      if (bt) {
        if (of32) mfma_gemm<true , float, 64><<<grd, blk, 0, stream>>>(A, lda, a_hi, a_lo, Bp, ldb, b_hi, b_lo,
            (float*)Cp, ldc, c_hi, c_lo, pstride, Ct, trans_hh, relu, K, nh, ksplit, scale, bias, bstride);
        else      mfma_gemm<true , short, 64><<<grd, blk, 0, stream>>>(A, lda, a_hi, a_lo, Bp, ldb, b_hi, b_lo,
            (short*)Cp, ldc, c_hi, c_lo, pstride, Ct, trans_hh, relu, K, nh, ksplit, scale, bias, bstride);
      } else {
        if (of32) mfma_gemm<false, float, 64><<<grd, blk, 0, stream>>>(A, lda, a_hi, a_lo, Bp, ldb, b_hi, b_lo,
            (float*)Cp, ldc, c_hi, c_lo, pstride, Ct, trans_hh, relu, K, nh, ksplit, scale, bias, bstride);
        else      mfma_gemm<false, short, 64><<<grd, blk, 0, stream>>>(A, lda, a_hi, a_lo, Bp, ldb, b_hi, b_lo,
            (short*)Cp, ldc, c_hi, c_lo, pstride, Ct, trans_hh, relu, K, nh, ksplit, scale, bias, bstride);
      }
    } else {
      if (bt) {
        if (of32) mfma_gemm<true , float, 128><<<grd, blk, 0, stream>>>(A, lda, a_hi, a_lo, Bp, ldb, b_hi, b_lo,
            (float*)Cp, ldc, c_hi, c_lo, pstride, Ct, trans_hh, relu, K, nh, ksplit, scale, bias, bstride);
        else      mfma_gemm<true , short, 128><<<grd, blk, 0, stream>>>(A, lda, a_hi, a_lo, Bp, ldb, b_hi, b_lo,
            (short*)Cp, ldc, c_hi, c_lo, pstride, Ct, trans_hh, relu, K, nh, ksplit, scale, bias, bstride);
      } else {
        if (of32) mfma_gemm<false, float, 128><<<grd, blk, 0, stream>>>(A, lda, a_hi, a_lo, Bp, ldb, b_hi, b_lo,
            (float*)Cp, ldc, c_hi, c_lo, pstride, Ct, trans_hh, relu, K, nh, ksplit, scale, bias, bstride);
        else      mfma_gemm<false, short, 128><<<grd, blk, 0, stream>>>(A, lda, a_hi, a_lo, Bp, ldb, b_hi, b_lo,
            (short*)Cp, ldc, c_hi, c_lo, pstride, Ct, trans_hh, relu, K, nh, ksplit, scale, bias, bstride);
      }
    }
  };

  auto attention = [&](const short* qsrc, const short* kvsrc, bool self,
                       const float* qkvw, const float* qkvb,
                       const float* ow, const float* ob,
                       float* resid, short* resid16, int causal,
                       const float* lng, const float* lnb) {
    if (self) {
      // fused Q,K,V (z=3); hh=0->Qb, hh=1->Kb (via c_lo), hh=2 -> transposed Vt
      gemm(false, false, true, 0, qsrc, D_, 0, 0, qkvw, HD_, 0, WQKV,
           Qb, HD_, 0, (long)(Kb - Qb), 0, Vt, 2,
           BT_, HD_, D_, 3, 3, 1, 1.0f, qkvb, HD_);
    } else {
      gemm(false, false, true, 0, qsrc, D_, 0, 0, qkvw, HD_, 0, 0,
           Qb, HD_, 0, 0, 0, nullptr, -1,
           BT_, HD_, D_, 1, 1, 1, 1.0f, qkvb, 0);
      gemm(false, false, true, 0, kvsrc, D_, 0, 0, qkvw + WQKV, HD_, 0, WQKV,
           Kb, HD_, 0, 0, 0, Vt, 1,
           BT_, HD_, D_, 2, 2, 1, 1.0f, qkvb + HD_, HD_);
    }
    // fused QK^T + softmax -> P (bf16)
    qksm_kernel<<<dim3(T_ / 64, BH_), blk, 0, stream>>>(Qb, Kb, Pb, causal);
    // O = P V  (B = V^T, k-contig)
    gemm(true, false, true, 0, Pb, T_, (long)H_ * (long)T_ * T_, (long)T_ * T_,
         Vt, BT_, T_, (long)D_ * BT_,
         Ob, HD_, THD, D_, 0, nullptr, -1,
         T_, D_, T_, BH_, H_, 1, 1.0f, nullptr, 0);
    // out-projection split-K=8 -> f32 partials in Sb; fused reduce+resid+LN
    gemm(false, true, true, 0, Ob, HD_, 0, 0, ow, D_, 0, 0,
         Sb, D_, 0, 0, (long)BT_ * D_, nullptr, -1,
         BT_, D_, HD_, 1, 1, 8, 1.0f, nullptr, 0);
    reduce_ln_kernel<<<dim3(BT_), blk, 0, stream>>>(
        Sb, (long)BT_ * D_, 8, ob, resid, resid16, lng, lnb);
  };

  auto ffn = [&](float* resid, short* resid16,
                 const float* w1, const float* b1,
                 const float* w2, const float* b2,
                 const float* lng, const float* lnb) {
    // FF1: fused bias+relu epilogue -> bf16 mid (BM=64, grid 256, no split-K)
    gemm(false, false, true, 1, resid16, D_, 0, 0, w1, F_, 0, 0,
         mid, F_, 0, 0, 0, nullptr, -1,
         BT_, F_, D_, 1, 1, 1, 1.0f, b1, 0);
    // FF2: split-K=8 -> f32 partials; fused reduce+resid+LN
    gemm(false, true, true, 0, mid, F_, 0, 0, w2, D_, 0, 0,
         Sb, D_, 0, 0, (long)BT_ * D_, nullptr, -1,
         BT_, D_, F_, 1, 1, 8, 1.0f, nullptr, 0);
    reduce_ln_kernel<<<dim3(BT_), blk, 0, stream>>>(
        Sb, (long)BT_ * D_, 8, b2, resid, resid16, lng, lnb);
  };

  // ---------------- encoder ----------------
  embed_kernel<<<dim3(BT_), blk, 0, stream>>>(x, enc_emb, h, hb16);
  for (int i = 0; i < L_; ++i) {
    attention(hb16, hb16, true,
              enc_qkv_w + (size_t)i * 3 * WQKV, enc_qkv_b + (size_t)i * 3 * HD_,
              enc_out_w + (size_t)i * HD_ * D_, enc_out_b + (size_t)i * D_,
              h, hb16, 0, enc_ln1_g + (size_t)i * D_, enc_ln1_b + (size_t)i * D_);
    ffn(h, hb16, enc_ff_w1 + (size_t)i * D_ * F_, enc_ff_b1 + (size_t)i * F_,
        enc_ff_w2 + (size_t)i * F_ * D_, enc_ff_b2 + (size_t)i * D_,
        enc_ln2_g + (size_t)i * D_, enc_ln2_b + (size_t)i * D_);
  }

  // ---------------- decoder ----------------
  embed_kernel<<<dim3(BT_), blk, 0, stream>>>(y, dec_emb, dd, db16);
  for (int i = 0; i < L_; ++i) {
    attention(db16, db16, true,
              dec_sa_qkv_w + (size_t)i * 3 * WQKV, dec_sa_qkv_b + (size_t)i * 3 * HD_,
              dec_sa_out_w + (size_t)i * HD_ * D_, dec_sa_out_b + (size_t)i * D_,
              dd, db16, 1, dec_ln1_g + (size_t)i * D_, dec_ln1_b + (size_t)i * D_);
    attention(db16, hb16, false,
              dec_ca_qkv_w + (size_t)i * 3 * WQKV, dec_ca_qkv_b + (size_t)i * 3 * HD_,
              dec_ca_out_w + (size_t)i * HD_ * D_, dec_ca_out_b + (size_t)i * D_,
              dd, db16, 0, dec_ln2_g + (size_t)i * D_, dec_ln2_b + (size_t)i * D_);
    ffn(dd, db16, dec_ff_w1 + (size_t)i * D_ * F_, dec_ff_b1 + (size_t)i * F_,
        dec_ff_w2 + (size_t)i * F_ * D_, dec_ff_b2 + (size_t)i * D_,
        dec_ln3_g + (size_t)i * D_, dec_ln3_b + (size_t)i * D_);
  }

  // ---------------- LM head -> f32 logits ----------------
  gemm(false, true, false, 0, db16, D_, 0, 0, head_w, V_, 0, 0,
       out, V_, 0, 0, 0, nullptr, -1,
       BT_, V_, D_, 1, 1, 1, 1.0f, head_b, 0);
}

// Round 10
// 2623.802 us; speedup vs baseline: 1.3307x; 1.2052x over previous
//
#include <hip/hip_runtime.h>
#include <hip/hip_bf16.h>

#define B_ 2
#define T_ 512
#define D_ 512
#define H_ 8
#define L_ 6
#define F_ 2048
#define V_ 32000
#define BT_ (B_ * T_)
#define HD_ (H_ * D_)
#define BH_ (B_ * H_)

typedef __attribute__((ext_vector_type(8))) short short8;
typedef __attribute__((ext_vector_type(4))) short short4v;
typedef __attribute__((ext_vector_type(4))) float f32x4;

__device__ __forceinline__ short f2b(float f) {
  __hip_bfloat16 h = __float2bfloat16(f);
  short u; __builtin_memcpy(&u, &h, 2); return u;
}
__device__ __forceinline__ void store_c(float* p, float v) { *p = v; }
__device__ __forceinline__ void store_c(short* p, float v) { *p = f2b(v); }

// direct global->LDS 16B async copy; LDS dest is wave-uniform base + lane*16
__device__ __forceinline__ void gload16(const void* g, void* l) {
  __builtin_amdgcn_global_load_lds(
      (const __attribute__((address_space(1))) void*)g,
      (__attribute__((address_space(3))) void*)l, 16, 0, 0);
}

// ---------------- embedding * sqrt(D) + sinusoidal PE (f32 + bf16 copies) ----------------
__global__ __launch_bounds__(256) void embed_kernel(
    const int* __restrict__ tok, const float* __restrict__ emb,
    float* __restrict__ out, short* __restrict__ out16)
{
  const int row = blockIdx.x;            // b*T + t
  const int t = row & (T_ - 1);
  const int token = tok[row];
  const float* e = emb + (size_t)token * D_;
  float* o = out + (size_t)row * D_;
  short* o16 = out16 + (size_t)row * D_;
  const float scale = sqrtf((float)D_);
  const float nl = -logf(10000.0f);
  for (int d = threadIdx.x; d < D_; d += 256) {
    int i = d >> 1;
    float wl = expf(nl * (2.0f * (float)i) / (float)D_);
    float ang = (float)t * wl;
    float pe = (d & 1) ? cosf(ang) : sinf(ang);
    float v = e[d] * scale + pe;
    o[d] = v; o16[d] = f2b(v);
  }
}

// ---------------- generic MFMA GEMM: global_load_lds staging, XOR-swizzled LDS ----------
// A: bf16 [.,K] k-contig (gload_lds). B: BTM ? bf16 [N][K] (gload_lds) : f32 [K][N]
// (reg+cvt staged). LDS layout: packet p = row*8 + slot, slot holds k-chunk
// (slot ^ (row&7)); ds_read applies same involution -> conflict-free.
// Double-buffered; loads for t+1 issued before MFMA(t). BM in {64,128}, BN=128.
template<bool BTM, typename OutT, int BM>
__global__ __launch_bounds__(256, BM == 128 ? 2 : 3) void mfma_gemm(
    const short* __restrict__ A, long lda, long a_hi, long a_lo,
    const void* __restrict__ Bv, long ldb, long b_hi, long b_lo,
    OutT* __restrict__ C, long ldc, long c_hi, long c_lo, long pstride,
    short* __restrict__ Ct, int trans_hh, int relu,
    int K, int nh, int ksplit, float scale,
    const float* __restrict__ bias, long bias_stride)
{
  constexpr int WRN = (BM == 128) ? 2 : 1;
  constexpr int WN  = (BM == 128) ? 64 : 32;
  constexpr int NR  = WN / 16;
  constexpr int CA  = BM / 32;          // gload calls per wave for A
  constexpr int PA  = BM * 8;           // A packets per buffer
  __shared__ short8 AsL[2 * PA];
  __shared__ short8 BsL[2 * 1024];
  const int tid = threadIdx.x;
  const int bh = blockIdx.z / ksplit;
  const int kz = blockIdx.z - bh * ksplit;
  const int bb = bh / nh, hh = bh - bb * nh;
  const short* Ab = A + (long)bb * a_hi + (long)hh * a_lo;
  const short* Bbs = (const short*)Bv + (long)bb * b_hi + (long)hh * b_lo;
  const float* Bbf = (const float*)Bv + (long)bb * b_hi + (long)hh * b_lo;
  OutT* Cb = C + (long)bb * c_hi + (long)hh * c_lo + (long)kz * pstride;

  // XCD-chunked bijective swizzle, y-major
  const int gx = gridDim.x, gy = gridDim.y;
  const int nwg = gx * gy;
  int lin = blockIdx.y * gx + blockIdx.x;
  {
    const int xcd = lin & 7, idx = lin >> 3;
    const int q = nwg >> 3, r = nwg & 7;
    lin = (xcd < r ? xcd * (q + 1) : r * (q + 1) + (xcd - r) * q) + idx;
  }
  const int bn = (lin / gy) * 128;
  const int bm = (lin % gy) * BM;

  const int klen = K / ksplit, kbase = kz * klen;
  const int lane = tid & 63, w4 = tid >> 6;
  const int wr = (WRN == 2) ? (w4 >> 1) : 0;
  const int wc = (WRN == 2) ? (w4 & 1) : w4;
  const int lg = lane >> 4, r16 = lane & 15;
  const int ncol = tid & 127, nsh = tid >> 7;

  float pbn[4][8];

  auto issueA = [&](int k0, int bo) {
#pragma unroll
    for (int u = 0; u < CA; ++u) {
      const int p = (w4 * CA + u) * 64 + lane;
      const int row = p >> 3, c = p & 7;
      const int cs = c ^ (row & 7);
      gload16(Ab + (long)(bm + row) * lda + (k0 + cs * 8),
              &AsL[bo + (w4 * CA + u) * 64]);
    }
  };
  auto issueB = [&](int k0, int bo) {
#pragma unroll
    for (int u = 0; u < 4; ++u) {
      const int p = (w4 * 4 + u) * 64 + lane;
      const int col = p >> 3, c = p & 7;
      const int cs = c ^ (col & 7);
      gload16(Bbs + (long)(bn + col) * ldb + (k0 + cs * 8),
              &BsL[bo + (w4 * 4 + u) * 64]);
    }
  };
  auto loadBn = [&](int k0) {
    const float* s = Bbf + (long)(k0 + nsh * 32) * ldb + (bn + ncol);
#pragma unroll
    for (int i = 0; i < 4; ++i)
#pragma unroll
      for (int j = 0; j < 8; ++j)
        pbn[i][j] = s[(long)(i * 8 + j) * ldb];
  };
  auto stageBn = [&](int bo) {
#pragma unroll
    for (int i = 0; i < 4; ++i) {
      const int cc = nsh * 4 + i;
      short8 v;
#pragma unroll
      for (int j = 0; j < 8; ++j) v[j] = f2b(pbn[i][j]);
      BsL[bo + ncol * 8 + (cc ^ (ncol & 7))] = v;
    }
  };

  f32x4 acc[4][NR] = {};
  auto domfma = [&](int abo, int bbo) {
#pragma unroll
    for (int kb = 0; kb < 2; ++kb) {
      const int ch = kb * 4 + lg;
      const int swz = ch ^ (r16 & 7);
      short8 a0 = AsL[abo + (wr * 64 +  0 + r16) * 8 + swz];
      short8 a1 = AsL[abo + (wr * 64 + 16 + r16) * 8 + swz];
      short8 a2 = AsL[abo + (wr * 64 + 32 + r16) * 8 + swz];
      short8 a3 = AsL[abo + (wr * 64 + 48 + r16) * 8 + swz];
#pragma unroll
      for (int n = 0; n < NR; ++n) {
        short8 bfr = BsL[bbo + (wc * WN + n * 16 + r16) * 8 + swz];
        acc[0][n] = __builtin_amdgcn_mfma_f32_16x16x32_bf16(a0, bfr, acc[0][n], 0, 0, 0);
        acc[1][n] = __builtin_amdgcn_mfma_f32_16x16x32_bf16(a1, bfr, acc[1][n], 0, 0, 0);
        acc[2][n] = __builtin_amdgcn_mfma_f32_16x16x32_bf16(a2, bfr, acc[2][n], 0, 0, 0);
        acc[3][n] = __builtin_amdgcn_mfma_f32_16x16x32_bf16(a3, bfr, acc[3][n], 0, 0, 0);
      }
    }
  };

  // prologue: stage step 0 into buffer 0
  issueA(kbase, 0);
  if constexpr (BTM) { issueB(kbase, 0); }
  else               { loadBn(kbase); stageBn(0); }
  __syncthreads();

  const int nsteps = klen >> 6;
  for (int t = 0; t < nsteps; ++t) {
    const bool more = (t + 1 < nsteps);
    const int cur = t & 1, nxt = cur ^ 1;
    if (more) {
      issueA(kbase + (t + 1) * 64, nxt * PA);
      if constexpr (BTM) issueB(kbase + (t + 1) * 64, nxt * 1024);
      else               loadBn(kbase + (t + 1) * 64);
    }
    domfma(cur * PA, cur * 1024);
    if (more) {
      if constexpr (!BTM) stageBn(nxt * 1024);
      __syncthreads();
    }
  }

  const float* bp = bias ? bias + (long)hh * bias_stride : nullptr;
  if (hh == trans_hh) {
    // transposed bf16 store: Ct[col][row]
#pragma unroll
    for (int m = 0; m < 4; ++m)
#pragma unroll
      for (int n = 0; n < NR; ++n) {
        const int col = bn + wc * WN + n * 16 + r16;
        const float badd = bp ? bp[col] : 0.0f;
        short4v sv;
#pragma unroll
        for (int rr = 0; rr < 4; ++rr) sv[rr] = f2b(acc[m][n][rr] * scale + badd);
        *(short4v*)(Ct + (long)col * BT_ + (bm + wr * 64 + m * 16 + lg * 4)) = sv;
      }
  } else {
#pragma unroll
    for (int m = 0; m < 4; ++m)
#pragma unroll
      for (int rr = 0; rr < 4; ++rr) {
        const int row = bm + wr * 64 + m * 16 + lg * 4 + rr;
        OutT* crow = Cb + (long)row * ldc + bn + wc * WN + r16;
#pragma unroll
        for (int n = 0; n < NR; ++n) {
          float v = acc[m][n][rr] * scale;
          if (bp) v += bp[bn + wc * WN + n * 16 + r16];
          if (relu) v = fmaxf(v, 0.0f);
          store_c(&crow[n * 16], v);
        }
      }
  }
}

// ---------------- split-K reduce + bias + relu -> bf16 (FFN mid) ----------------
__global__ __launch_bounds__(256) void reduce_bias_relu_bf16(
    const float* __restrict__ P, long pstride, int ks,
    const float* __restrict__ bias, short* __restrict__ out, long mn, int N)
{
  const long i = ((long)blockIdx.x * 256 + threadIdx.x) * 4;
  if (i >= mn) return;
  float4 s = *(const float4*)(P + i);
  for (int z = 1; z < ks; ++z) {
    float4 t = *(const float4*)(P + (long)z * pstride + i);
    s.x += t.x; s.y += t.y; s.z += t.z; s.w += t.w;
  }
  const int col = (int)(i % N);
  s.x += bias[col]; s.y += bias[col + 1]; s.z += bias[col + 2]; s.w += bias[col + 3];
  short4v o;
  o[0] = f2b(fmaxf(s.x, 0.f)); o[1] = f2b(fmaxf(s.y, 0.f));
  o[2] = f2b(fmaxf(s.z, 0.f)); o[3] = f2b(fmaxf(s.w, 0.f));
  *(short4v*)(out + i) = o;
}

// ---- fused: x = resid + bias + sum_z partial; resid(f32) = LN(x)*g+b; + bf16 copy ----
__global__ __launch_bounds__(256) void reduce_ln_kernel(
    const float* __restrict__ P, long pstride, int ks,
    const float* __restrict__ bias, float* __restrict__ hbuf, short* __restrict__ h16,
    const float* __restrict__ gam, const float* __restrict__ bet)
{
  __shared__ float red[256];
  const int row = blockIdx.x, tid = threadIdx.x;
  const long base = (long)row * D_;
  float s0 = hbuf[base + tid] + bias[tid];
  float s1 = hbuf[base + tid + 256] + bias[tid + 256];
  for (int z = 0; z < ks; ++z) {
    s0 += P[(long)z * pstride + base + tid];
    s1 += P[(long)z * pstride + base + tid + 256];
  }
  red[tid] = s0 + s1; __syncthreads();
  for (int o = 128; o > 0; o >>= 1) { if (tid < o) red[tid] += red[tid + o]; __syncthreads(); }
  const float mean = red[0] * (1.0f / D_); __syncthreads();
  const float d0 = s0 - mean, d1 = s1 - mean;
  red[tid] = d0 * d0 + d1 * d1; __syncthreads();
  for (int o = 128; o > 0; o >>= 1) { if (tid < o) red[tid] += red[tid + o]; __syncthreads(); }
  const float inv = rsqrtf(red[0] * (1.0f / D_) + 1e-6f);
  const float v0 = d0 * inv * gam[tid] + bet[tid];
  const float v1 = d1 * inv * gam[tid + 256] + bet[tid + 256];
  hbuf[base + tid] = v0;       h16[base + tid] = f2b(v0);
  hbuf[base + tid + 256] = v1; h16[base + tid + 256] = f2b(v1);
}

// ------- single-pass row softmax (f32 in, bf16 out); causal k<=q; tail -> 0 -------
__global__ __launch_bounds__(256) void softmax_kernel(
    const float* __restrict__ S, short* __restrict__ P, int causal)
{
  __shared__ float red[256];
  const int q = blockIdx.x, bh = blockIdx.y, tid = threadIdx.x;
  const float* row = S + ((size_t)bh * T_ + q) * T_;
  short* prow = P + ((size_t)bh * T_ + q) * T_;
  const int n = causal ? (q + 1) : T_;
  const float v0 = row[tid], v1 = row[tid + 256];
  const bool in0 = tid < n, in1 = (tid + 256) < n;
  red[tid] = fmaxf(in0 ? v0 : -3.0e38f, in1 ? v1 : -3.0e38f);
  __syncthreads();
  for (int o = 128; o > 0; o >>= 1) { if (tid < o) red[tid] = fmaxf(red[tid], red[tid + o]); __syncthreads(); }
  const float m = red[0]; __syncthreads();
  const float e0 = in0 ? expf(v0 - m) : 0.0f;
  const float e1 = in1 ? expf(v1 - m) : 0.0f;
  red[tid] = e0 + e1; __syncthreads();
  for (int o = 128; o > 0; o >>= 1) { if (tid < o) red[tid] += red[tid + o]; __syncthreads(); }
  const float inv = 1.0f / red[0];
  prow[tid] = f2b(e0 * inv);
  prow[tid + 256] = f2b(e1 * inv);
}

extern "C" void kernel_launch(void* const* d_in, const int* in_sizes, int n_in,
                              void* d_out, int out_size, void* d_ws, size_t ws_size,
                              hipStream_t stream)
{
  const int*   x         = (const int*)d_in[0];
  const int*   y         = (const int*)d_in[1];
  const float* enc_emb   = (const float*)d_in[2];
  const float* dec_emb   = (const float*)d_in[3];
  const float* enc_qkv_w = (const float*)d_in[4];
  const float* enc_qkv_b = (const float*)d_in[5];
  const float* enc_out_w = (const float*)d_in[6];
  const float* enc_out_b = (const float*)d_in[7];
  const float* enc_ln1_g = (const float*)d_in[8];
  const float* enc_ln1_b = (const float*)d_in[9];
  const float* enc_ff_w1 = (const float*)d_in[10];
  const float* enc_ff_b1 = (const float*)d_in[11];
  const float* enc_ff_w2 = (const float*)d_in[12];
  const float* enc_ff_b2 = (const float*)d_in[13];
  const float* enc_ln2_g = (const float*)d_in[14];
  const float* enc_ln2_b = (const float*)d_in[15];
  const float* dec_sa_qkv_w = (const float*)d_in[16];
  const float* dec_sa_qkv_b = (const float*)d_in[17];
  const float* dec_sa_out_w = (const float*)d_in[18];
  const float* dec_sa_out_b = (const float*)d_in[19];
  const float* dec_ln1_g = (const float*)d_in[20];
  const float* dec_ln1_b = (const float*)d_in[21];
  const float* dec_ca_qkv_w = (const float*)d_in[22];
  const float* dec_ca_qkv_b = (const float*)d_in[23];
  const float* dec_ca_out_w = (const float*)d_in[24];
  const float* dec_ca_out_b = (const float*)d_in[25];
  const float* dec_ln2_g = (const float*)d_in[26];
  const float* dec_ln2_b = (const float*)d_in[27];
  const float* dec_ff_w1 = (const float*)d_in[28];
  const float* dec_ff_b1 = (const float*)d_in[29];
  const float* dec_ff_w2 = (const float*)d_in[30];
  const float* dec_ff_b2 = (const float*)d_in[31];
  const float* dec_ln3_g = (const float*)d_in[32];
  const float* dec_ln3_b = (const float*)d_in[33];
  const float* head_w    = (const float*)d_in[34];
  const float* head_b    = (const float*)d_in[35];
  float* out = (float*)d_out;

  // ---- workspace carve-up ----
  char* wsb = (char*)d_ws;
  size_t off = 0;
  auto carve = [&](size_t bytes) { char* p = wsb + off; off += (bytes + 255) & ~255ull; return p; };
  float* h    = (float*)carve((size_t)BT_ * D_ * 4);
  float* dd   = (float*)carve((size_t)BT_ * D_ * 4);
  short* hb16 = (short*)carve((size_t)BT_ * D_ * 2);
  short* db16 = (short*)carve((size_t)BT_ * D_ * 2);
  short* Qb   = (short*)carve((size_t)BT_ * HD_ * 2);
  short* Kb   = (short*)carve((size_t)BT_ * HD_ * 2);
  short* Vt   = (short*)carve((size_t)HD_ * BT_ * 2);
  float* Sb   = (float*)carve((size_t)BH_ * T_ * T_ * 4);  // S + split-K partials
  short* Pb   = (short*)carve((size_t)BH_ * T_ * T_ * 2);
  short* Ob   = Qb;   // Q dead after QK^T
  short* mid  = Qb;   // attn buffers dead during FFN
  (void)ws_size;

  dim3 blk(256);
  const long TT  = (long)T_ * T_;
  const long THD = (long)T_ * HD_;
  const long WQKV = (long)D_ * HD_;

  auto gemm = [&](bool bt, bool of32, bool bm64, int relu,
                  const short* A, long lda, long a_hi, long a_lo,
                  const void* Bp, long ldb, long b_hi, long b_lo,
                  void* Cp, long ldc, long c_hi, long c_lo, long pstride,
                  short* Ct, int trans_hh,
                  int M, int N, int K, int batch, int nh, int ksplit,
                  float scale, const float* bias, long bstride) {
    dim3 grd(N / 128, M / (bm64 ? 64 : 128), batch * ksplit);
    if (bm64) {
      if (bt) {
        if (of32) mfma_gemm<true , float, 64><<<grd, blk, 0, stream>>>(A, lda, a_hi, a_lo, Bp, ldb, b_hi, b_lo,
            (float*)Cp, ldc, c_hi, c_lo, pstride, Ct, trans_hh, relu, K, nh, ksplit, scale, bias, bstride);
        else      mfma_gemm<true , short, 64><<<grd, blk, 0, stream>>>(A, lda, a_hi, a_lo, Bp, ldb, b_hi, b_lo,
            (short*)Cp, ldc, c_hi, c_lo, pstride, Ct, trans_hh, relu, K, nh, ksplit, scale, bias, bstride);
      } else {
        if (of32) mfma_gemm<false, float, 64><<<grd, blk, 0, stream>>>(A, lda, a_hi, a_lo, Bp, ldb, b_hi, b_lo,
            (float*)Cp, ldc, c_hi, c_lo, pstride, Ct, trans_hh, relu, K, nh, ksplit, scale, bias, bstride);
        else      mfma_gemm<false, short, 64><<<grd, blk, 0, stream>>>(A, lda, a_hi, a_lo, Bp, ldb, b_hi, b_lo,
            (short*)Cp, ldc, c_hi, c_lo, pstride, Ct, trans_hh, relu, K, nh, ksplit, scale, bias, bstride);
      }
    } else {
      if (of32) mfma_gemm<false, float, 128><<<grd, blk, 0, stream>>>(A, lda, a_hi, a_lo, Bp, ldb, b_hi, b_lo,
          (float*)Cp, ldc, c_hi, c_lo, pstride, Ct, trans_hh, relu, K, nh, ksplit, scale, bias, bstride);
      else      mfma_gemm<false, short, 128><<<grd, blk, 0, stream>>>(A, lda, a_hi, a_lo, Bp, ldb, b_hi, b_lo,
          (short*)Cp, ldc, c_hi, c_lo, pstride, Ct, trans_hh, relu, K, nh, ksplit, scale, bias, bstride);
    }
  };

  auto attention = [&](const short* qsrc, const short* kvsrc, bool self,
                       const float* qkvw, const float* qkvb,
                       const float* ow, const float* ob,
                       float* resid, short* resid16, int causal,
                       const float* lng, const float* lnb) {
    if (self) {
      // fused Q,K,V (z=3); hh=0->Qb, hh=1->Kb (via c_lo), hh=2 -> transposed Vt
      gemm(false, false, true, 0, qsrc, D_, 0, 0, qkvw, HD_, 0, WQKV,
           Qb, HD_, 0, (long)(Kb - Qb), 0, Vt, 2,
           BT_, HD_, D_, 3, 3, 1, 1.0f, qkvb, HD_);
    } else {
      gemm(false, false, true, 0, qsrc, D_, 0, 0, qkvw, HD_, 0, 0,
           Qb, HD_, 0, 0, 0, nullptr, -1,
           BT_, HD_, D_, 1, 1, 1, 1.0f, qkvb, 0);
      gemm(false, false, true, 0, kvsrc, D_, 0, 0, qkvw + WQKV, HD_, 0, WQKV,
           Kb, HD_, 0, 0, 0, Vt, 1,
           BT_, HD_, D_, 2, 2, 1, 1.0f, qkvb + HD_, HD_);
    }
    // S = Q K^T / sqrt(D)
    gemm(true, true, true, 0, Qb, HD_, THD, D_, Kb, HD_, THD, D_,
         Sb, T_, (long)H_ * TT, TT, 0, nullptr, -1,
         T_, T_, D_, BH_, H_, 1, 0.044194173824159216f, nullptr, 0);
    softmax_kernel<<<dim3(T_, BH_), blk, 0, stream>>>(Sb, Pb, causal);
    // O = P V  (B = V^T, k-contig)
    gemm(true, false, true, 0, Pb, T_, (long)H_ * TT, TT, Vt, BT_, T_, (long)D_ * BT_,
         Ob, HD_, THD, D_, 0, nullptr, -1,
         T_, D_, T_, BH_, H_, 1, 1.0f, nullptr, 0);
    // out-projection split-K=8 -> f32 partials in Sb; fused reduce+resid+LN
    gemm(false, true, true, 0, Ob, HD_, 0, 0, ow, D_, 0, 0,
         Sb, D_, 0, 0, (long)BT_ * D_, nullptr, -1,
         BT_, D_, HD_, 1, 1, 8, 1.0f, nullptr, 0);
    reduce_ln_kernel<<<dim3(BT_), blk, 0, stream>>>(
        Sb, (long)BT_ * D_, 8, ob, resid, resid16, lng, lnb);
  };

  auto ffn = [&](float* resid, short* resid16,
                 const float* w1, const float* b1,
                 const float* w2, const float* b2,
                 const float* lng, const float* lnb) {
    gemm(false, true, true, 0, resid16, D_, 0, 0, w1, F_, 0, 0,
         Sb, F_, 0, 0, (long)BT_ * F_, nullptr, -1,
         BT_, F_, D_, 1, 1, 2, 1.0f, nullptr, 0);
    reduce_bias_relu_bf16<<<dim3(BT_ * F_ / 1024), blk, 0, stream>>>(
        Sb, (long)BT_ * F_, 2, b1, mid, (long)BT_ * F_, F_);
    gemm(false, true, true, 0, mid, F_, 0, 0, w2, D_, 0, 0,
         Sb, D_, 0, 0, (long)BT_ * D_, nullptr, -1,
         BT_, D_, F_, 1, 1, 8, 1.0f, nullptr, 0);
    reduce_ln_kernel<<<dim3(BT_), blk, 0, stream>>>(
        Sb, (long)BT_ * D_, 8, b2, resid, resid16, lng, lnb);
  };

  // ---------------- encoder ----------------
  embed_kernel<<<dim3(BT_), blk, 0, stream>>>(x, enc_emb, h, hb16);
  for (int i = 0; i < L_; ++i) {
    attention(hb16, hb16, true,
              enc_qkv_w + (size_t)i * 3 * WQKV, enc_qkv_b + (size_t)i * 3 * HD_,
              enc_out_w + (size_t)i * HD_ * D_, enc_out_b + (size_t)i * D_,
              h, hb16, 0, enc_ln1_g + (size_t)i * D_, enc_ln1_b + (size_t)i * D_);
    ffn(h, hb16, enc_ff_w1 + (size_t)i * D_ * F_, enc_ff_b1 + (size_t)i * F_,
        enc_ff_w2 + (size_t)i * F_ * D_, enc_ff_b2 + (size_t)i * D_,
        enc_ln2_g + (size_t)i * D_, enc_ln2_b + (size_t)i * D_);
  }

  // ---------------- decoder ----------------
  embed_kernel<<<dim3(BT_), blk, 0, stream>>>(y, dec_emb, dd, db16);
  for (int i = 0; i < L_; ++i) {
    attention(db16, db16, true,
              dec_sa_qkv_w + (size_t)i * 3 * WQKV, dec_sa_qkv_b + (size_t)i * 3 * HD_,
              dec_sa_out_w + (size_t)i * HD_ * D_, dec_sa_out_b + (size_t)i * D_,
              dd, db16, 1, dec_ln1_g + (size_t)i * D_, dec_ln1_b + (size_t)i * D_);
    attention(db16, hb16, false,
              dec_ca_qkv_w + (size_t)i * 3 * WQKV, dec_ca_qkv_b + (size_t)i * 3 * HD_,
              dec_ca_out_w + (size_t)i * HD_ * D_, dec_ca_out_b + (size_t)i * D_,
              dd, db16, 0, dec_ln2_g + (size_t)i * D_, dec_ln2_b + (size_t)i * D_);
    ffn(dd, db16, dec_ff_w1 + (size_t)i * D_ * F_, dec_ff_b1 + (size_t)i * F_,
        dec_ff_w2 + (size_t)i * F_ * D_, dec_ff_b2 + (size_t)i * D_,
        dec_ln3_g + (size_t)i * D_, dec_ln3_b + (size_t)i * D_);
  }

  // ---------------- LM head -> f32 logits ----------------
  gemm(false, true, false, 0, db16, D_, 0, 0, head_w, V_, 0, 0,
       out, V_, 0, 0, 0, nullptr, -1,
       BT_, V_, D_, 1, 1, 1, 1.0f, head_b, 0);
}